// Round 1
// baseline (529.067 us; speedup 1.0000x reference)
//
#include <hip/hip_runtime.h>
#include <climits>

#define PAD_IDX 1
#define SEP_ID 4

// Stage 1: one block (256 threads) per batch row. Each thread owns 16
// consecutive tokens; block-scan (Hillis-Steele over LDS) combines
// per-thread partials: running MAX of sep index, running MIN of first
// padding index. Then each thread replays its 16 elements with the carry.
__global__ __launch_bounds__(256) void pos_kernel(const int* __restrict__ tokens,
                                                  int* __restrict__ pos,
                                                  int seq_len) {
    const int row  = blockIdx.x;
    const int t    = threadIdx.x;
    const int CH   = seq_len >> 8;          // 16 elements/thread at seq_len=4096
    const int rbase = row * seq_len;
    const int ebase = t * CH;

    int toks[16];
    const int4* tp = (const int4*)(tokens + rbase + ebase);
    #pragma unroll
    for (int k = 0; k < 4; ++k) {
        int4 v = tp[k];
        toks[k*4+0] = v.x; toks[k*4+1] = v.y; toks[k*4+2] = v.z; toks[k*4+3] = v.w;
    }

    // Per-thread partials.
    int localMaxSep = 0;          // identity for running-max of sep_j (ref uses 0)
    int localMinPad = INT_MAX;    // identity for first-pad index
    #pragma unroll
    for (int k = 0; k < 16; ++k) {
        int j = ebase + k;
        if (toks[k] == SEP_ID)  localMaxSep = max(localMaxSep, j);
        if (toks[k] == PAD_IDX) localMinPad = min(localMinPad, j);
    }

    __shared__ int sMax[256];
    __shared__ int sMin[256];
    sMax[t] = localMaxSep;
    sMin[t] = localMinPad;
    __syncthreads();
    for (int off = 1; off < 256; off <<= 1) {
        int vM = 0, vN = INT_MAX;
        if (t >= off) { vM = sMax[t - off]; vN = sMin[t - off]; }
        __syncthreads();
        sMax[t] = max(sMax[t], vM);
        sMin[t] = min(sMin[t], vN);
        __syncthreads();
    }
    // Exclusive carries for this thread's chunk.
    int lastSep  = (t > 0) ? sMax[t - 1] : 0;
    int firstPad = (t > 0) ? sMin[t - 1] : INT_MAX;

    int outv[16];
    #pragma unroll
    for (int k = 0; k < 16; ++k) {
        int j   = ebase + k;
        int tok = toks[k];
        if (tok == PAD_IDX) firstPad = min(firstPad, j);   // cumprod is inclusive
        if (tok == SEP_ID)  lastSep  = max(lastSep, j);    // inclusive scan of sep_j
        outv[k] = (firstPad <= j) ? 1 : (j - lastSep + 2);
    }
    int4* op = (int4*)(pos + rbase + ebase);
    #pragma unroll
    for (int k = 0; k < 4; ++k) {
        op[k] = make_int4(outv[k*4+0], outv[k*4+1], outv[k*4+2], outv[k*4+3]);
    }
}

// Stage 2: one block per output row (b,s). 256 threads x float4 = 4 KB row.
// pos[blockIdx.x] is block-uniform -> scalar load; table rows live in L2/L3.
__global__ __launch_bounds__(256) void gather_kernel(const float4* __restrict__ w,
                                                     const int* __restrict__ pos,
                                                     float4* __restrict__ out) {
    const int row = blockIdx.x;
    const int d   = threadIdx.x;
    const int p   = pos[row];
    out[(size_t)row * 256 + d] = w[(size_t)p * 256 + d];
}

extern "C" void kernel_launch(void* const* d_in, const int* in_sizes, int n_in,
                              void* d_out, int out_size, void* d_ws, size_t ws_size,
                              hipStream_t stream) {
    const int*   tokens  = (const int*)d_in[0];    // [rows, 4096] int32
    const float* weights = (const float*)d_in[1];  // [4098, 1024] fp32
    float*       out     = (float*)d_out;          // [rows, 4096, 1024] fp32

    const int seq_len = 4096;
    const int rows    = in_sizes[0] / seq_len;     // 32

    int* pos = (int*)d_ws;                         // rows*seq_len*4 = 512 KB scratch

    pos_kernel<<<rows, 256, 0, stream>>>(tokens, pos, seq_len);
    gather_kernel<<<rows * seq_len, 256, 0, stream>>>((const float4*)weights, pos,
                                                      (float4*)out);
}